// Round 2
// baseline (436.957 us; speedup 1.0000x reference)
//
#include <hip/hip_runtime.h>
#include <math.h>

#define BB 16
#define TT 2048
#define FF 512
#define CC 256
#define NEG 10
#define NSTEPS 12
#define COPIES 11
#define MM (BB * TT)
#define ROWSTRIDE 260  // 256 + 4 pad: float4-aligned, breaks power-of-2 bank stride

// ---------------- Kernel 1: tl = true_latent @ Wl + bl  (f32 GEMM 32768x512x256)
__global__ __launch_bounds__(256) void proj_gemm_kernel(
    const float* __restrict__ A,     // [MM, FF]
    const float* __restrict__ W,     // [FF, CC]
    const float* __restrict__ bias,  // [CC]
    float* __restrict__ Out) {       // [MM, CC]
  __shared__ __align__(16) float As[16][68];  // k-major
  __shared__ __align__(16) float Bs[16][64];
  const int tid = threadIdx.x;
  const int bm = blockIdx.x * 64;
  const int bn = blockIdx.y * 64;
  const int tx = tid & 15, ty = tid >> 4;
  const int arow = tid >> 2;          // 0..63
  const int akcol = (tid & 3) << 2;   // 0,4,8,12
  const int bkrow = tid >> 4;         // 0..15
  const int bcol = (tid & 15) << 2;   // 0..60
  float acc[4][4] = {};
  for (int k0 = 0; k0 < FF; k0 += 16) {
    const float4 av = *reinterpret_cast<const float4*>(&A[(size_t)(bm + arow) * FF + k0 + akcol]);
    const float4 bv = *reinterpret_cast<const float4*>(&W[(size_t)(k0 + bkrow) * CC + bn + bcol]);
    __syncthreads();
    As[akcol + 0][arow] = av.x;
    As[akcol + 1][arow] = av.y;
    As[akcol + 2][arow] = av.z;
    As[akcol + 3][arow] = av.w;
    *reinterpret_cast<float4*>(&Bs[bkrow][bcol]) = bv;
    __syncthreads();
#pragma unroll
    for (int kk = 0; kk < 16; ++kk) {
      const float4 a4 = *reinterpret_cast<const float4*>(&As[kk][ty << 2]);
      const float4 b4 = *reinterpret_cast<const float4*>(&Bs[kk][tx << 2]);
      const float a[4] = {a4.x, a4.y, a4.z, a4.w};
      const float b[4] = {b4.x, b4.y, b4.z, b4.w};
#pragma unroll
      for (int i = 0; i < 4; ++i)
#pragma unroll
        for (int j = 0; j < 4; ++j) acc[i][j] = fmaf(a[i], b[j], acc[i][j]);
    }
  }
  const float4 bias4 = *reinterpret_cast<const float4*>(&bias[bn + (tx << 2)]);
  const float bz[4] = {bias4.x, bias4.y, bias4.z, bias4.w};
#pragma unroll
  for (int i = 0; i < 4; ++i) {
    float4 o;
    o.x = acc[i][0] + bz[0];
    o.y = acc[i][1] + bz[1];
    o.z = acc[i][2] + bz[2];
    o.w = acc[i][3] + bz[3];
    *reinterpret_cast<float4*>(&Out[(size_t)(bm + (ty << 2) + i) * CC + bn + (tx << 2)]) = o;
  }
}

#define FMA4(S, A, C)            \
  S.x = fmaf(A.x, C.x, S.x);     \
  S.y = fmaf(A.y, C.y, S.y);     \
  S.z = fmaf(A.z, C.z, S.z);     \
  S.w = fmaf(A.w, C.w, S.w);

__device__ __forceinline__ float hsum4(float4 s) { return (s.x + s.y) + (s.z + s.w); }

// ---------------- Kernel 2: per-(b, t') block -> 12x11 logits -> (lse - logit0) row sums
__global__ __launch_bounds__(256) void cpc_loss_kernel(
    const float* __restrict__ ctx,  // [BB, TT, CC]
    const float* __restrict__ tl,   // [BB, TT, CC]
    const int* __restrict__ negs,   // [BB, NEG, TT]
    const float* __restrict__ Ws,   // [NSTEPS]
    const float* __restrict__ bs,   // [NSTEPS]
    float* __restrict__ partials) { // [MM]
  __shared__ __align__(16) float rows[(NSTEPS + COPIES) * ROWSTRIDE];  // 12 ctx rows then 11 target rows
  __shared__ float sPart[4][NSTEPS][NSTEPS];  // k-split partial dots (12x12, col 11 unused)
  __shared__ float sTsum[COPIES];
  __shared__ float sContrib[NSTEPS];
  const int blk = blockIdx.x;
  const int b = blk >> 11;         // / TT
  const int tp = blk & (TT - 1);   // target time t'
  const int tid = threadIdx.x;

  // Cooperative load: 23 rows x 64 float4 (coalesced 1KB segments per row)
  for (int idx = tid; idx < (NSTEPS + COPIES) * (CC / 4); idx += 256) {
    const int r = idx >> 6;   // row 0..22
    const int k4 = idx & 63;  // float4 index within row
    float4 v;
    if (r < NSTEPS) {
      const int t = tp - r;  // ctx row for step i=r is pred time t'-i
      v = (t >= 0) ? *reinterpret_cast<const float4*>(&ctx[((size_t)b * TT + t) * CC + (k4 << 2)])
                   : make_float4(0.f, 0.f, 0.f, 0.f);
    } else {
      const int cp = r - NSTEPS;
      const int u = (cp == 0) ? tp : negs[((size_t)b * NEG + (cp - 1)) * TT + tp];
      v = *reinterpret_cast<const float4*>(&tl[((size_t)b * TT + u) * CC + (k4 << 2)]);
    }
    *reinterpret_cast<float4*>(&rows[r * ROWSTRIDE + (k4 << 2)]) = v;
  }
  __syncthreads();

  if (tid < 144) {
    // 2x2-blocked dot tiles with 4-way k-split: tile (ri, rc) covers i in {2ri, 2ri+1},
    // cp in {2rc, 2rc+1}; thread reads 4 rows x 64 floats instead of flat 2 x 256.
    const int kg = tid / 36;
    const int r = tid - kg * 36;
    const int ri = r / 6;
    const int rc = r - ri * 6;
    const int i0 = ri * 2, i1 = i0 + 1;
    const int cp0 = rc * 2;
    const int cp1 = (cp0 + 1 < COPIES) ? cp0 + 1 : COPIES - 1;  // clamp (duplicate work, discarded)
    const float* a0 = &rows[i0 * ROWSTRIDE + kg * 64];
    const float* a1 = &rows[i1 * ROWSTRIDE + kg * 64];
    const float* c0 = &rows[(NSTEPS + cp0) * ROWSTRIDE + kg * 64];
    const float* c1 = &rows[(NSTEPS + cp1) * ROWSTRIDE + kg * 64];
    float4 s00 = make_float4(0.f, 0.f, 0.f, 0.f);
    float4 s01 = make_float4(0.f, 0.f, 0.f, 0.f);
    float4 s10 = make_float4(0.f, 0.f, 0.f, 0.f);
    float4 s11 = make_float4(0.f, 0.f, 0.f, 0.f);
#pragma unroll
    for (int k = 0; k < 64; k += 4) {
      const float4 A0 = *reinterpret_cast<const float4*>(&a0[k]);
      const float4 A1 = *reinterpret_cast<const float4*>(&a1[k]);
      const float4 C0 = *reinterpret_cast<const float4*>(&c0[k]);
      const float4 C1 = *reinterpret_cast<const float4*>(&c1[k]);
      FMA4(s00, A0, C0)
      FMA4(s01, A0, C1)
      FMA4(s10, A1, C0)
      FMA4(s11, A1, C1)
    }
    sPart[kg][i0][cp0] = hsum4(s00);
    sPart[kg][i0][cp1] = hsum4(s01);
    sPart[kg][i1][cp0] = hsum4(s10);
    sPart[kg][i1][cp1] = hsum4(s11);
  } else if (tid < 144 + COPIES) {  // 11 target-row sums (bs term), runs concurrently
    const int cp = tid - 144;
    const float* rb = &rows[(NSTEPS + cp) * ROWSTRIDE];
    float s0 = 0.f, s1 = 0.f, s2 = 0.f, s3 = 0.f;
    for (int k = 0; k < CC; k += 4) {
      const float4 c = *reinterpret_cast<const float4*>(&rb[k]);
      s0 += c.x; s1 += c.y; s2 += c.z; s3 += c.w;
    }
    sTsum[cp] = (s0 + s1) + (s2 + s3);
  }
  __syncthreads();

  if (tid < NSTEPS) {  // one logits row per step i (valid iff i <= t')
    const int i = tid;
    float contrib = 0.f;
    if (i <= tp) {
      const float w = Ws[i], bbias = bs[i];
      float lg[COPIES];
      float m = -INFINITY;
#pragma unroll
      for (int cp = 0; cp < COPIES; ++cp) {
        const float d = (sPart[0][i][cp] + sPart[1][i][cp]) + (sPart[2][i][cp] + sPart[3][i][cp]);
        lg[cp] = fmaf(w, d, bbias * sTsum[cp]);
        m = fmaxf(m, lg[cp]);
      }
      float s = 0.f;
#pragma unroll
      for (int cp = 0; cp < COPIES; ++cp) s += expf(lg[cp] - m);
      contrib = m + logf(s) - lg[0];
    }
    sContrib[i] = contrib;
  }
  __syncthreads();

  if (tid == 0) {
    float tot = 0.f;
#pragma unroll
    for (int i = 0; i < NSTEPS; ++i) tot += sContrib[i];
    partials[blk] = tot;
  }
}

// ---------------- Kernel 3: deterministic reduction of 32768 block partials (double accum)
__global__ __launch_bounds__(256) void reduce_kernel(const float* __restrict__ partials,
                                                     float* __restrict__ out) {
  __shared__ double sred[256];
  double acc = 0.0;
  for (int idx = threadIdx.x; idx < MM; idx += 256) acc += (double)partials[idx];
  sred[threadIdx.x] = acc;
  __syncthreads();
  for (int s = 128; s > 0; s >>= 1) {
    if (threadIdx.x < s) sred[threadIdx.x] += sred[threadIdx.x + s];
    __syncthreads();
  }
  if (threadIdx.x == 0) out[0] = (float)sred[0];
}

extern "C" void kernel_launch(void* const* d_in, const int* in_sizes, int n_in,
                              void* d_out, int out_size, void* d_ws, size_t ws_size,
                              hipStream_t stream) {
  const float* true_latent = (const float*)d_in[0];     // [BB,TT,FF]
  const float* context_latent = (const float*)d_in[1];  // [BB,TT,CC]
  const float* Wl = (const float*)d_in[2];              // [FF,CC]
  const float* bl = (const float*)d_in[3];              // [CC]
  const float* Ws = (const float*)d_in[4];              // [NSTEPS]
  const float* bs = (const float*)d_in[5];              // [NSTEPS]
  const int* negs = (const int*)d_in[6];                // [BB,NEG,TT]

  float* tl = (float*)d_ws;                                             // [MM, CC] = 32 MB
  float* partials = (float*)((char*)d_ws + (size_t)MM * CC * sizeof(float));  // [MM] = 128 KB

  dim3 g1(MM / 64, CC / 64);
  proj_gemm_kernel<<<g1, 256, 0, stream>>>(true_latent, Wl, bl, tl);
  cpc_loss_kernel<<<MM, 256, 0, stream>>>(context_latent, tl, negs, Ws, bs, partials);
  reduce_kernel<<<1, 256, 0, stream>>>(partials, (float*)d_out);
}